// Round 3
// baseline (5100.709 us; speedup 1.0000x reference)
//
#include <hip/hip_runtime.h>

// ResidualQuantizer: 3-level RVQ, levels 0/1 argmin, level 2 = 50-iter log-domain
// Sinkhorn in potential form, computed in the exp2 domain:
//   vt_ij = twot*cross(r_i,c_j) + w_j           (twot = 2*t*log2e)
//   sigma_j = sum_i 2^(vt_ij - rowLSE2_i)       (terms <= 1)
//   w_j    += log2(B/K) - log2(sigma_j)
//   codes2_i = argmax_j vt_ij
// sigma accumulated as fixed-point u64 atomics (order-independent => deterministic).
// Codebook fragments are PINNED into VGPRs via empty asm (the compiler otherwise
// rematerializes the global loads inside the row loop -> ~290 VMEM/wave).

#define BSZ   262144
#define DIM   32
#define KK    256
#define CHUNK 128
#define NBLK  (BSZ / CHUNK)   // 2048
#define LROW  36              // padded LDS row stride (144B, 16B-aligned)
#define SKEPS 0.003f
#define NIT   50

// workspace float offsets
#define WS_SSQ  0
#define WS_MINK 1
#define WS_MAXK 2
#define WS_TWOT 3
#define WS_W0   256   // 256 floats (initial w, log2-scaled)
#define WS_WA   512   // w slot A
#define WS_WB   768   // w slot B
#define WS_SIGB 4096  // byte offset of 3 x 256 u64 sigma slots

// d_out float offsets (return order: codes0, codes1, codes2, quantized, loss)
#define OC0   0
#define OC1   BSZ
#define OC2   (2 * BSZ)
#define OQ    (3 * BSZ)
#define OLOSS (3 * BSZ + BSZ * DIM)

#if __has_builtin(__builtin_amdgcn_exp2f)
#define EXP2(x) __builtin_amdgcn_exp2f(x)
#else
#define EXP2(x) exp2f(x)
#endif

#if __has_builtin(__builtin_amdgcn_update_dpp)
#define ROR16(x, N)                                                            \
  __int_as_float(__builtin_amdgcn_update_dpp(__float_as_int(x),                \
                 __float_as_int(x), 0x120 + (N), 0xF, 0xF, false))
#else
#define ROR16(x, N) __shfl_xor((x), (N))
#endif

__device__ __forceinline__ float wred_max(float x) {
  x = fmaxf(x, ROR16(x, 1));
  x = fmaxf(x, ROR16(x, 2));
  x = fmaxf(x, ROR16(x, 4));
  x = fmaxf(x, ROR16(x, 8));
  x = fmaxf(x, __shfl_xor(x, 16));
  x = fmaxf(x, __shfl_xor(x, 32));
  return x;
}
__device__ __forceinline__ float wred_min(float x) {
  x = fminf(x, ROR16(x, 1));
  x = fminf(x, ROR16(x, 2));
  x = fminf(x, ROR16(x, 4));
  x = fminf(x, ROR16(x, 8));
  x = fminf(x, __shfl_xor(x, 16));
  x = fminf(x, __shfl_xor(x, 32));
  return x;
}
__device__ __forceinline__ float wred_sum(float x) {
  x += ROR16(x, 1);
  x += ROR16(x, 2);
  x += ROR16(x, 4);
  x += ROR16(x, 8);
  x += __shfl_xor(x, 16);
  x += __shfl_xor(x, 32);
  return x;
}

__device__ __forceinline__ unsigned fkey(float f) {
  unsigned b = __float_as_uint(f);
  return (b & 0x80000000u) ? ~b : (b | 0x80000000u);
}
__device__ __forceinline__ float fkeyinv(unsigned k) {
  return __uint_as_float((k & 0x80000000u) ? (k ^ 0x80000000u) : ~k);
}

// Load this lane's 4 codebook columns scaled by `scale` and PIN them in VGPRs.
__device__ __forceinline__ void load_cbregs_pin(const float* __restrict__ cb, int lane,
                                                float scale, float cbr[4][DIM]) {
#pragma unroll
  for (int c = 0; c < 4; ++c) {
    const float4* p = reinterpret_cast<const float4*>(cb + (4 * lane + c) * DIM);
#pragma unroll
    for (int k = 0; k < 8; ++k) {
      float4 v = p[k];
      cbr[c][4 * k + 0] = v.x * scale;
      cbr[c][4 * k + 1] = v.y * scale;
      cbr[c][4 * k + 2] = v.z * scale;
      cbr[c][4 * k + 3] = v.w * scale;
    }
  }
#pragma unroll
  for (int c = 0; c < 4; ++c)
#pragma unroll
    for (int i = 0; i < DIM; ++i)
      asm volatile("" : "+v"(cbr[c][i]));   // opaque def: no rematerialization
}

// c2 derived from the pinned registers (scale must be 1 for true norms).
__device__ __forceinline__ void cb_norms(const float cbr[4][DIM], float c2[4]) {
#pragma unroll
  for (int c = 0; c < 4; ++c) {
    float s = 0.f;
#pragma unroll
    for (int i = 0; i < DIM; ++i) s = fmaf(cbr[c][i], cbr[c][i], s);
    c2[c] = s;
  }
}

// 4 rows x 4 cols dot accumulate; zr = first row, consecutive rows stride LROW.
__device__ __forceinline__ void dot4x4(const float* zr, const float cbr[4][DIM],
                                       float v[4][4]) {
#pragma unroll
  for (int d = 0; d < DIM; d += 4) {
#pragma unroll
    for (int q = 0; q < 4; ++q) {
      float4 a = *reinterpret_cast<const float4*>(zr + q * LROW + d);
#pragma unroll
      for (int c = 0; c < 4; ++c) {
        v[q][c] = fmaf(cbr[c][d + 0], a.x, v[q][c]);
        v[q][c] = fmaf(cbr[c][d + 1], a.y, v[q][c]);
        v[q][c] = fmaf(cbr[c][d + 2], a.z, v[q][c]);
        v[q][c] = fmaf(cbr[c][d + 3], a.w, v[q][c]);
      }
    }
  }
}

__global__ void init_k(unsigned* __restrict__ wsu, unsigned long long* __restrict__ sig0) {
  sig0[threadIdx.x] = 0ull;
  if (threadIdx.x == 0) {
    wsu[WS_SSQ]  = 0u;
    wsu[WS_MINK] = 0xFFFFFFFFu;
    wsu[WS_MAXK] = 0u;
  }
}

__device__ __forceinline__ void argmin_phase(const float* __restrict__ cb, const float* zl,
                                             const float* rsq, int* codel, int lane, int wid) {
  float cbr[4][DIM], c2[4];
  load_cbregs_pin(cb, lane, 1.0f, cbr);
  cb_norms(cbr, c2);
  for (int rb = 0; rb < 8; ++rb) {
    const int r0 = wid * 32 + rb * 4;
    float v[4][4];
#pragma unroll
    for (int q = 0; q < 4; ++q) { v[q][0] = 0.f; v[q][1] = 0.f; v[q][2] = 0.f; v[q][3] = 0.f; }
    dot4x4(&zl[r0 * LROW], cbr, v);
    float d0[4], d1[4], d2[4], d3[4], bq[4], mq[4];
#pragma unroll
    for (int q = 0; q < 4; ++q) {
      float r2 = rsq[r0 + q];
      d0[q] = fmaf(-2.f, v[q][0], r2 + c2[0]);
      d1[q] = fmaf(-2.f, v[q][1], r2 + c2[1]);
      d2[q] = fmaf(-2.f, v[q][2], r2 + c2[2]);
      d3[q] = fmaf(-2.f, v[q][3], r2 + c2[3]);
      bq[q] = fminf(fminf(d0[q], d1[q]), fminf(d2[q], d3[q]));
    }
#pragma unroll
    for (int q = 0; q < 4; ++q) mq[q] = wred_min(bq[q]);
#pragma unroll
    for (int q = 0; q < 4; ++q) {
      int cbi = (d0[q] == mq[q]) ? 0 : ((d1[q] == mq[q]) ? 1 : ((d2[q] == mq[q]) ? 2 : 3));
      unsigned long long bl = __ballot(bq[q] == mq[q]);
      int src = __ffsll(bl) - 1;
      int code = __shfl(4 * lane + cbi, src);
      if (lane == 0) codel[r0 + q] = code;
    }
  }
}

// zl[row] -= cb[code[row]]; accumulate per-row squared norms into rsq (pre-zeroed).
__device__ __forceinline__ void remap_phase(const float* __restrict__ cb, float* zl,
                                            float* rsq, const int* codel, int tid) {
  int row = tid & (CHUNK - 1);
  int half = tid >> 7;
  const float4* cbg = reinterpret_cast<const float4*>(cb + codel[row] * DIM + half * 16);
  float4* zr = reinterpret_cast<float4*>(&zl[row * LROW + half * 16]);
  float local = 0.f;
#pragma unroll
  for (int k = 0; k < 4; ++k) {
    float4 cv = cbg[k];
    float4 v = zr[k];
    v.x -= cv.x; v.y -= cv.y; v.z -= cv.z; v.w -= cv.w;
    zr[k] = v;
    local = fmaf(v.x, v.x, local); local = fmaf(v.y, v.y, local);
    local = fmaf(v.z, v.z, local); local = fmaf(v.w, v.w, local);
  }
  atomicAdd(&rsq[row], local);
}

__global__ __launch_bounds__(256, 2) void stageA_k(const float* __restrict__ z,
                                                   const float* __restrict__ cb0,
                                                   const float* __restrict__ cb1,
                                                   const float* __restrict__ cb2,
                                                   float* __restrict__ out,
                                                   unsigned* __restrict__ wsu,
                                                   float* __restrict__ wsf) {
  __shared__ float zl[CHUNK * LROW];
  __shared__ float rsq[CHUNK];
  __shared__ int codel[CHUNK];
  __shared__ float red[4];
  const int tid = threadIdx.x, lane = tid & 63, wid = tid >> 6;
  const long base = (long)blockIdx.x * CHUNK;

#pragma unroll
  for (int g = 0; g < 4; ++g) {
    int f4 = g * 256 + tid;
    float4 v = reinterpret_cast<const float4*>(z + base * DIM)[f4];
    int row = f4 >> 3, d = (f4 & 7) * 4;
    *reinterpret_cast<float4*>(&zl[row * LROW + d]) = v;
  }
  __syncthreads();
  if (tid < CHUNK) {
    float s = 0.f;
#pragma unroll
    for (int d = 0; d < DIM; ++d) { float x = zl[tid * LROW + d]; s = fmaf(x, x, s); }
    rsq[tid] = s;
  }
  __syncthreads();

  float loss_acc = 0.f;

  // ---- level 0
  argmin_phase(cb0, zl, rsq, codel, lane, wid);
  __syncthreads();
  if (tid < CHUNK) { out[OC0 + base + tid] = (float)codel[tid]; rsq[tid] = 0.f; }
  __syncthreads();
  remap_phase(cb0, zl, rsq, codel, tid);
  __syncthreads();
  if (tid < CHUNK) loss_acc += rsq[tid];

  // ---- level 1
  argmin_phase(cb1, zl, rsq, codel, lane, wid);
  __syncthreads();
  if (tid < CHUNK) { out[OC1 + base + tid] = (float)codel[tid]; rsq[tid] = 0.f; }
  __syncthreads();
  remap_phase(cb1, zl, rsq, codel, tid);
  __syncthreads();
  if (tid < CHUNK) loss_acc += rsq[tid];

  // residual2 -> staged in quantized region of d_out (float4)
#pragma unroll
  for (int g = 0; g < 4; ++g) {
    int f4 = g * 256 + tid;
    int row = f4 >> 3, d = (f4 & 7) * 4;
    reinterpret_cast<float4*>(out + OQ + base * DIM)[f4] =
        *reinterpret_cast<const float4*>(&zl[row * LROW + d]);
  }

  // ---- level 2 global min/max of distances
  {
    float cbr[4][DIM], c2[4];
    load_cbregs_pin(cb2, lane, 1.0f, cbr);
    cb_norms(cbr, c2);
    float dmn = 3.4e38f, dmx = -3.4e38f;
    for (int rb = 0; rb < 8; ++rb) {
      const int r0 = wid * 32 + rb * 4;
      float v[4][4];
#pragma unroll
      for (int q = 0; q < 4; ++q) { v[q][0] = 0.f; v[q][1] = 0.f; v[q][2] = 0.f; v[q][3] = 0.f; }
      dot4x4(&zl[r0 * LROW], cbr, v);
#pragma unroll
      for (int q = 0; q < 4; ++q) {
        float r2 = rsq[r0 + q];
#pragma unroll
        for (int c = 0; c < 4; ++c) {
          float dd = fmaf(-2.f, v[q][c], r2 + c2[c]);
          dmn = fminf(dmn, dd);
          dmx = fmaxf(dmx, dd);
        }
      }
    }
    dmn = wred_min(dmn);
    dmx = wred_max(dmx);
    if (lane == 0) {
      atomicMin(&wsu[WS_MINK], fkey(dmn));
      atomicMax(&wsu[WS_MAXK], fkey(dmx));
    }
  }

  loss_acc = wred_sum(loss_acc);
  if (lane == 0) red[wid] = loss_acc;
  __syncthreads();
  if (tid == 0) atomicAdd(&wsf[WS_SSQ], red[0] + red[1] + red[2] + red[3]);
}

__global__ void prep_k(const float* __restrict__ cb2, unsigned* __restrict__ wsu,
                       float* __restrict__ wsf) {
  int j = threadIdx.x;  // 256 threads
  float dmin = fkeyinv(wsu[WS_MINK]);
  float dmax = fkeyinv(wsu[WS_MAXK]);
  float mid = (dmax + dmin) * 0.5f;
  float amp = fmaxf(dmax - mid, 1e-5f);
  float t = 1.0f / (amp * SKEPS);
  const float L2E = 1.4426950408889634f;
  if (j == 0) wsf[WS_TWOT] = 2.0f * t * L2E;
  float s = 0.f;
#pragma unroll
  for (int d = 0; d < DIM; ++d) { float c = cb2[j * DIM + d]; s = fmaf(c, c, s); }
  wsf[WS_W0 + j] = -t * L2E * s;
}

__global__ __launch_bounds__(256, 2) void iter_k(const float* __restrict__ resid,
                                                 const float* __restrict__ cb2,
                                                 const float* __restrict__ wsf,
                                                 const float* __restrict__ w_rd,
                                                 float* __restrict__ w_wr,
                                                 const unsigned long long* __restrict__ s_rd,
                                                 unsigned long long* __restrict__ s_wr,
                                                 unsigned long long* __restrict__ s_zr,
                                                 int first) {
  __shared__ float zl[CHUNK * LROW];
  __shared__ float wsh[KK];
  __shared__ float sigsh[4][KK];
  const int tid = threadIdx.x, lane = tid & 63, wid = tid >> 6;
  const long base = (long)blockIdx.x * CHUNK;

  {
    // w_k = w_{k-1} + log2(B/K) + 24 - log2(sigma_raw); 24 undoes the 2^24 fixed-point.
    float wj = first ? w_rd[tid]
                     : w_rd[tid] + 34.0f - log2f(fmaxf((float)s_rd[tid], 1.0f));
    wsh[tid] = wj;
    if (blockIdx.x == 0) { w_wr[tid] = wj; s_zr[tid] = 0ull; }
  }
#pragma unroll
  for (int g = 0; g < 4; ++g) {
    int f4 = g * 256 + tid;
    float4 vv = reinterpret_cast<const float4*>(resid + base * DIM)[f4];
    int row = f4 >> 3, d = (f4 & 7) * 4;
    *reinterpret_cast<float4*>(&zl[row * LROW + d]) = vv;
  }
  const float twot = wsf[WS_TWOT];
  float cbr[4][DIM];
  load_cbregs_pin(cb2, lane, twot, cbr);
  __syncthreads();
  float wc[4];
#pragma unroll
  for (int c = 0; c < 4; ++c) wc[c] = wsh[4 * lane + c];

  float sg[4] = {0.f, 0.f, 0.f, 0.f};
  for (int rb = 0; rb < 8; ++rb) {
    const int r0 = wid * 32 + rb * 4;
    float v[4][4];
#pragma unroll
    for (int q = 0; q < 4; ++q) { v[q][0] = wc[0]; v[q][1] = wc[1]; v[q][2] = wc[2]; v[q][3] = wc[3]; }
    dot4x4(&zl[r0 * LROW], cbr, v);
    float m[4], ss[4];
#pragma unroll
    for (int q = 0; q < 4; ++q)
      m[q] = fmaxf(fmaxf(v[q][0], v[q][1]), fmaxf(v[q][2], v[q][3]));
#pragma unroll
    for (int q = 0; q < 4; ++q) m[q] = wred_max(m[q]);
#pragma unroll
    for (int q = 0; q < 4; ++q) {
      v[q][0] = EXP2(v[q][0] - m[q]); v[q][1] = EXP2(v[q][1] - m[q]);
      v[q][2] = EXP2(v[q][2] - m[q]); v[q][3] = EXP2(v[q][3] - m[q]);
      ss[q] = (v[q][0] + v[q][1]) + (v[q][2] + v[q][3]);
    }
#pragma unroll
    for (int q = 0; q < 4; ++q) ss[q] = wred_sum(ss[q]);
#pragma unroll
    for (int q = 0; q < 4; ++q) {
      float ri = __builtin_amdgcn_rcpf(ss[q]);
      sg[0] = fmaf(v[q][0], ri, sg[0]);
      sg[1] = fmaf(v[q][1], ri, sg[1]);
      sg[2] = fmaf(v[q][2], ri, sg[2]);
      sg[3] = fmaf(v[q][3], ri, sg[3]);
    }
  }
#pragma unroll
  for (int c = 0; c < 4; ++c) sigsh[wid][4 * lane + c] = sg[c];
  __syncthreads();
  float s = sigsh[0][tid] + sigsh[1][tid] + sigsh[2][tid] + sigsh[3][tid];
  // fixed-point u64 accumulation: order-independent => deterministic
  atomicAdd(&s_wr[tid], (unsigned long long)fmaf(s, 16777216.0f, 0.5f));
}

__global__ __launch_bounds__(256, 2) void final_k(const float* __restrict__ z,
                                                  const float* __restrict__ cb2,
                                                  float* __restrict__ out,
                                                  const float* __restrict__ wsf,
                                                  float* __restrict__ wssq,
                                                  const float* __restrict__ w_rd,
                                                  const unsigned long long* __restrict__ s_rd) {
  __shared__ float zl[CHUNK * LROW];
  __shared__ float wsh[KK];
  __shared__ int codel[CHUNK];
  __shared__ float red[4];
  const int tid = threadIdx.x, lane = tid & 63, wid = tid >> 6;
  const long base = (long)blockIdx.x * CHUNK;

  wsh[tid] = w_rd[tid] + 34.0f - log2f(fmaxf((float)s_rd[tid], 1.0f));

  const float* resid = out + OQ;
#pragma unroll
  for (int g = 0; g < 4; ++g) {
    int f4 = g * 256 + tid;
    float4 vv = reinterpret_cast<const float4*>(resid + base * DIM)[f4];
    int row = f4 >> 3, d = (f4 & 7) * 4;
    *reinterpret_cast<float4*>(&zl[row * LROW + d]) = vv;
  }
  const float twot = wsf[WS_TWOT];
  float cbr[4][DIM];
  load_cbregs_pin(cb2, lane, twot, cbr);
  __syncthreads();
  float wc[4];
#pragma unroll
  for (int c = 0; c < 4; ++c) wc[c] = wsh[4 * lane + c];

  for (int rb = 0; rb < 8; ++rb) {
    const int r0 = wid * 32 + rb * 4;
    float v[4][4];
#pragma unroll
    for (int q = 0; q < 4; ++q) { v[q][0] = wc[0]; v[q][1] = wc[1]; v[q][2] = wc[2]; v[q][3] = wc[3]; }
    dot4x4(&zl[r0 * LROW], cbr, v);
    float bq[4], mq[4];
#pragma unroll
    for (int q = 0; q < 4; ++q)
      bq[q] = fmaxf(fmaxf(v[q][0], v[q][1]), fmaxf(v[q][2], v[q][3]));
#pragma unroll
    for (int q = 0; q < 4; ++q) mq[q] = wred_max(bq[q]);
#pragma unroll
    for (int q = 0; q < 4; ++q) {
      int cbi = (v[q][0] == mq[q]) ? 0 : ((v[q][1] == mq[q]) ? 1 : ((v[q][2] == mq[q]) ? 2 : 3));
      unsigned long long bl = __ballot(bq[q] == mq[q]);
      int src = __ffsll(bl) - 1;
      int code = __shfl(4 * lane + cbi, src);
      if (lane == 0) codel[r0 + q] = code;
    }
  }
  __syncthreads();
  if (tid < CHUNK) out[OC2 + base + tid] = (float)codel[tid];
  float loss_acc = 0.f;
#pragma unroll
  for (int g = 0; g < 4; ++g) {
    int f4 = g * 256 + tid;
    int row = f4 >> 3, d = (f4 & 7) * 4;
    float4 e = *reinterpret_cast<const float4*>(cb2 + codel[row] * DIM + d);
    float4 r = *reinterpret_cast<const float4*>(&zl[row * LROW + d]);
    float4 zv = reinterpret_cast<const float4*>(z + base * DIM)[f4];
    float4 q;
    q.x = zv.x - r.x + e.x; q.y = zv.y - r.y + e.y;
    q.z = zv.z - r.z + e.z; q.w = zv.w - r.w + e.w;
    reinterpret_cast<float4*>(out + OQ + base * DIM)[f4] = q;
    float rx = r.x - e.x, ry = r.y - e.y, rz = r.z - e.z, rw = r.w - e.w;
    loss_acc = fmaf(rx, rx, loss_acc); loss_acc = fmaf(ry, ry, loss_acc);
    loss_acc = fmaf(rz, rz, loss_acc); loss_acc = fmaf(rw, rw, loss_acc);
  }
  loss_acc = wred_sum(loss_acc);
  if (lane == 0) red[wid] = loss_acc;
  __syncthreads();
  if (tid == 0) atomicAdd(&wssq[WS_SSQ], red[0] + red[1] + red[2] + red[3]);
}

__global__ void losswrite_k(float* __restrict__ out, const float* __restrict__ wsf) {
  if (threadIdx.x == 0) out[OLOSS] = 1.25f * wsf[WS_SSQ] / 8388608.0f;
}

extern "C" void kernel_launch(void* const* d_in, const int* in_sizes, int n_in,
                              void* d_out, int out_size, void* d_ws, size_t ws_size,
                              hipStream_t stream) {
  const float* z   = (const float*)d_in[0];
  const float* cb0 = (const float*)d_in[1];
  const float* cb1 = (const float*)d_in[2];
  const float* cb2 = (const float*)d_in[3];
  float* out = (float*)d_out;
  float* wsf = (float*)d_ws;
  unsigned* wsu = (unsigned*)d_ws;
  unsigned long long* sig = (unsigned long long*)((char*)d_ws + WS_SIGB);

  init_k<<<1, 256, 0, stream>>>(wsu, sig);  // zeroes sigma slot 0
  stageA_k<<<NBLK, 256, 0, stream>>>(z, cb0, cb1, cb2, out, wsu, wsf);
  prep_k<<<1, 256, 0, stream>>>(cb2, wsu, wsf);
  for (int it = 0; it < NIT; ++it) {
    const float* w_rd = (it == 0) ? (wsf + WS_W0) : (wsf + WS_WA + ((it - 1) & 1) * KK);
    float* w_wr = wsf + WS_WA + (it & 1) * KK;
    const unsigned long long* s_rd = sig + KK * ((it + 2) % 3);
    unsigned long long* s_wr = sig + KK * (it % 3);
    unsigned long long* s_zr = sig + KK * ((it + 1) % 3);
    iter_k<<<NBLK, 256, 0, stream>>>(out + OQ, cb2, wsf, w_rd, w_wr, s_rd, s_wr, s_zr,
                                     it == 0 ? 1 : 0);
  }
  final_k<<<NBLK, 256, 0, stream>>>(z, cb2, out, wsf, wsf,
                                    wsf + WS_WA + ((NIT - 1) & 1) * KK,
                                    sig + KK * ((NIT - 1) % 3));
  losswrite_k<<<1, 64, 0, stream>>>(out, wsf);
}

// Round 4
// 2333.928 us; speedup vs baseline: 2.1855x; 2.1855x over previous
//
#include <hip/hip_runtime.h>

// ResidualQuantizer: 3-level RVQ. Levels 0/1 = argmin (VALU). Level 2 = 50-iter
// log-domain Sinkhorn in potential form (exp2 domain):
//   vt_ij = (2t*log2e)*(r_i . c_j) + w_j
//   sigma_j = sum_i 2^(vt_ij - rowLSE2_i);  w_j += log2(B/K) - log2(sigma_j)
// iter_k computes the dots on the MATRIX pipe: fp16x4 error-compensated split
// (r = rh+rl, twot*c = ch+cl; 4x mfma_f32_16x16x32_f16, fp32 accumulate).
// A/B fragments use one consistent presumed k-mapping on both sides -> result
// invariant to the true HW k-permutation. C/D layout: col=lane&15,
// row=(lane>>4)*4+reg (HW-verified).
// sigma accumulated as fixed-point u64 atomics (deterministic).

#define BSZ   262144
#define DIM   32
#define KK    256
#define CHUNK 128
#define NBLK  (BSZ / CHUNK)    // 2048 (stageA)
#define ITBLK 256
#define NIBLK (BSZ / ITBLK)    // 1024 (iter_k)
#define LROW  36
#define SKEPS 0.003f
#define NIT   50

// workspace float offsets
#define WS_SSQ  0
#define WS_MINK 1
#define WS_MAXK 2
#define WS_TWOT 3
#define WS_W0   256
#define WS_WA   512
#define WS_SIGB 4096   // byte offset: 3 x 256 u64 sigma slots (6 KB)
#define WS_BHU  8192   // u32 offset of B-frag hi plane (4096 u32)
#define WS_BLU  12288  // u32 offset of B-frag lo plane

// d_out float offsets (codes0, codes1, codes2, quantized, loss)
#define OC0   0
#define OC1   BSZ
#define OC2   (2 * BSZ)
#define OQ    (3 * BSZ)
#define OLOSS (3 * BSZ + BSZ * DIM)
// A-frag planes live in the quantized region until final_k overwrites it
#define OU_AH (3u * BSZ)               // u32 index
#define OU_AL (3u * BSZ + 4194304u)    // u32 index

typedef _Float16 half8 __attribute__((ext_vector_type(8)));
typedef float f32x4 __attribute__((ext_vector_type(4)));

#if __has_builtin(__builtin_amdgcn_exp2f)
#define EXP2(x) __builtin_amdgcn_exp2f(x)
#else
#define EXP2(x) exp2f(x)
#endif

#if __has_builtin(__builtin_amdgcn_update_dpp)
#define ROR16(x, N)                                                            \
  __int_as_float(__builtin_amdgcn_update_dpp(__float_as_int(x),                \
                 __float_as_int(x), 0x120 + (N), 0xF, 0xF, false))
#else
#define ROR16(x, N) __shfl_xor((x), (N))
#endif

__device__ __forceinline__ float wred_max(float x) {
  x = fmaxf(x, ROR16(x, 1)); x = fmaxf(x, ROR16(x, 2));
  x = fmaxf(x, ROR16(x, 4)); x = fmaxf(x, ROR16(x, 8));
  x = fmaxf(x, __shfl_xor(x, 16)); x = fmaxf(x, __shfl_xor(x, 32));
  return x;
}
__device__ __forceinline__ float wred_min(float x) {
  x = fminf(x, ROR16(x, 1)); x = fminf(x, ROR16(x, 2));
  x = fminf(x, ROR16(x, 4)); x = fminf(x, ROR16(x, 8));
  x = fminf(x, __shfl_xor(x, 16)); x = fminf(x, __shfl_xor(x, 32));
  return x;
}
__device__ __forceinline__ float wred_sum(float x) {
  x += ROR16(x, 1); x += ROR16(x, 2); x += ROR16(x, 4); x += ROR16(x, 8);
  x += __shfl_xor(x, 16); x += __shfl_xor(x, 32);
  return x;
}
// 16-lane-group reductions (pure DPP, stay within lane rows)
__device__ __forceinline__ float g16_max(float x) {
  x = fmaxf(x, ROR16(x, 1)); x = fmaxf(x, ROR16(x, 2));
  x = fmaxf(x, ROR16(x, 4)); x = fmaxf(x, ROR16(x, 8));
  return x;
}
__device__ __forceinline__ float g16_sum(float x) {
  x += ROR16(x, 1); x += ROR16(x, 2); x += ROR16(x, 4); x += ROR16(x, 8);
  return x;
}

__device__ __forceinline__ unsigned fkey(float f) {
  unsigned b = __float_as_uint(f);
  return (b & 0x80000000u) ? ~b : (b | 0x80000000u);
}
__device__ __forceinline__ float fkeyinv(unsigned k) {
  return __uint_as_float((k & 0x80000000u) ? (k ^ 0x80000000u) : ~k);
}
__device__ __forceinline__ unsigned pk2h(_Float16 a, _Float16 b) {
  unsigned short ua = __builtin_bit_cast(unsigned short, a);
  unsigned short ub = __builtin_bit_cast(unsigned short, b);
  return (unsigned)ua | ((unsigned)ub << 16);
}

__device__ __forceinline__ void load_cbregs_pin(const float* __restrict__ cb, int lane,
                                                float scale, float cbr[4][DIM]) {
#pragma unroll
  for (int c = 0; c < 4; ++c) {
    const float4* p = reinterpret_cast<const float4*>(cb + (4 * lane + c) * DIM);
#pragma unroll
    for (int k = 0; k < 8; ++k) {
      float4 v = p[k];
      cbr[c][4 * k + 0] = v.x * scale; cbr[c][4 * k + 1] = v.y * scale;
      cbr[c][4 * k + 2] = v.z * scale; cbr[c][4 * k + 3] = v.w * scale;
    }
  }
}
__device__ __forceinline__ void cb_norms(const float cbr[4][DIM], float c2[4]) {
#pragma unroll
  for (int c = 0; c < 4; ++c) {
    float s = 0.f;
#pragma unroll
    for (int i = 0; i < DIM; ++i) s = fmaf(cbr[c][i], cbr[c][i], s);
    c2[c] = s;
  }
}
__device__ __forceinline__ void dot4x4(const float* zr, const float cbr[4][DIM],
                                       float v[4][4]) {
#pragma unroll
  for (int d = 0; d < DIM; d += 4) {
#pragma unroll
    for (int q = 0; q < 4; ++q) {
      float4 a = *reinterpret_cast<const float4*>(zr + q * LROW + d);
#pragma unroll
      for (int c = 0; c < 4; ++c) {
        v[q][c] = fmaf(cbr[c][d + 0], a.x, v[q][c]);
        v[q][c] = fmaf(cbr[c][d + 1], a.y, v[q][c]);
        v[q][c] = fmaf(cbr[c][d + 2], a.z, v[q][c]);
        v[q][c] = fmaf(cbr[c][d + 3], a.w, v[q][c]);
      }
    }
  }
}

__global__ void init_k(unsigned* __restrict__ wsu, unsigned long long* __restrict__ sig0) {
  sig0[threadIdx.x] = 0ull;
  if (threadIdx.x == 0) {
    wsu[WS_SSQ] = 0u; wsu[WS_MINK] = 0xFFFFFFFFu; wsu[WS_MAXK] = 0u;
  }
}

__device__ __forceinline__ void argmin_phase(const float* __restrict__ cb, const float* zl,
                                             const float* rsq, int* codel, int lane, int wid) {
  float cbr[4][DIM], c2[4];
  load_cbregs_pin(cb, lane, 1.0f, cbr);
  cb_norms(cbr, c2);
  for (int rb = 0; rb < 8; ++rb) {
    const int r0 = wid * 32 + rb * 4;
    float v[4][4];
#pragma unroll
    for (int q = 0; q < 4; ++q) { v[q][0] = 0.f; v[q][1] = 0.f; v[q][2] = 0.f; v[q][3] = 0.f; }
    dot4x4(&zl[r0 * LROW], cbr, v);
    float d0[4], d1[4], d2[4], d3[4], bq[4], mq[4];
#pragma unroll
    for (int q = 0; q < 4; ++q) {
      float r2 = rsq[r0 + q];
      d0[q] = fmaf(-2.f, v[q][0], r2 + c2[0]);
      d1[q] = fmaf(-2.f, v[q][1], r2 + c2[1]);
      d2[q] = fmaf(-2.f, v[q][2], r2 + c2[2]);
      d3[q] = fmaf(-2.f, v[q][3], r2 + c2[3]);
      bq[q] = fminf(fminf(d0[q], d1[q]), fminf(d2[q], d3[q]));
    }
#pragma unroll
    for (int q = 0; q < 4; ++q) mq[q] = wred_min(bq[q]);
#pragma unroll
    for (int q = 0; q < 4; ++q) {
      int cbi = (d0[q] == mq[q]) ? 0 : ((d1[q] == mq[q]) ? 1 : ((d2[q] == mq[q]) ? 2 : 3));
      unsigned long long bl = __ballot(bq[q] == mq[q]);
      int src = __ffsll(bl) - 1;
      int code = __shfl(4 * lane + cbi, src);
      if (lane == 0) codel[r0 + q] = code;
    }
  }
}

__device__ __forceinline__ void remap_phase(const float* __restrict__ cb, float* zl,
                                            float* rsq, const int* codel, int tid) {
  int row = tid & (CHUNK - 1);
  int half = tid >> 7;
  const float4* cbg = reinterpret_cast<const float4*>(cb + codel[row] * DIM + half * 16);
  float4* zr = reinterpret_cast<float4*>(&zl[row * LROW + half * 16]);
  float local = 0.f;
#pragma unroll
  for (int k = 0; k < 4; ++k) {
    float4 cv = cbg[k];
    float4 v = zr[k];
    v.x -= cv.x; v.y -= cv.y; v.z -= cv.z; v.w -= cv.w;
    zr[k] = v;
    local = fmaf(v.x, v.x, local); local = fmaf(v.y, v.y, local);
    local = fmaf(v.z, v.z, local); local = fmaf(v.w, v.w, local);
  }
  atomicAdd(&rsq[row], local);
}

__global__ __launch_bounds__(256, 2) void stageA_k(const float* __restrict__ z,
                                                   const float* __restrict__ cb0,
                                                   const float* __restrict__ cb1,
                                                   const float* __restrict__ cb2,
                                                   float* __restrict__ out,
                                                   unsigned* __restrict__ outu,
                                                   unsigned* __restrict__ wsu,
                                                   float* __restrict__ wsf) {
  __shared__ float zl[CHUNK * LROW];
  __shared__ float rsq[CHUNK];
  __shared__ int codel[CHUNK];
  __shared__ float red[4];
  const int tid = threadIdx.x, lane = tid & 63, wid = tid >> 6;
  const long base = (long)blockIdx.x * CHUNK;

#pragma unroll
  for (int g = 0; g < 4; ++g) {
    int f4 = g * 256 + tid;
    float4 v = reinterpret_cast<const float4*>(z + base * DIM)[f4];
    int row = f4 >> 3, d = (f4 & 7) * 4;
    *reinterpret_cast<float4*>(&zl[row * LROW + d]) = v;
  }
  __syncthreads();
  if (tid < CHUNK) {
    float s = 0.f;
#pragma unroll
    for (int d = 0; d < DIM; ++d) { float x = zl[tid * LROW + d]; s = fmaf(x, x, s); }
    rsq[tid] = s;
  }
  __syncthreads();

  float loss_acc = 0.f;

  // ---- level 0
  argmin_phase(cb0, zl, rsq, codel, lane, wid);
  __syncthreads();
  if (tid < CHUNK) { out[OC0 + base + tid] = (float)codel[tid]; rsq[tid] = 0.f; }
  __syncthreads();
  remap_phase(cb0, zl, rsq, codel, tid);
  __syncthreads();
  if (tid < CHUNK) loss_acc += rsq[tid];

  // ---- level 1
  argmin_phase(cb1, zl, rsq, codel, lane, wid);
  __syncthreads();
  if (tid < CHUNK) { out[OC1 + base + tid] = (float)codel[tid]; rsq[tid] = 0.f; }
  __syncthreads();
  remap_phase(cb1, zl, rsq, codel, tid);
  __syncthreads();
  if (tid < CHUNK) loss_acc += rsq[tid];

  // ---- r2 -> fp16 hi/lo A-fragment planes (presumed k-map: k = (l>>4)*8 + j)
#pragma unroll
  for (int g2 = 0; g2 < 8; ++g2) {
    int slot = g2 * 256 + tid;        // 2048 slots/block
    int b = slot >> 8;                // batch-in-block 0..7
    int l = (slot >> 2) & 63;
    int u = slot & 3;
    int row = b * 16 + (l & 15);
    int k = (l >> 4) * 8 + u * 2;
    float x0 = zl[row * LROW + k], x1 = zl[row * LROW + k + 1];
    _Float16 h0 = (_Float16)x0, h1 = (_Float16)x1;
    _Float16 q0 = (_Float16)(x0 - (float)h0), q1 = (_Float16)(x1 - (float)h1);
    unsigned gbase = ((unsigned)blockIdx.x * 8u + (unsigned)b) * 256u + (unsigned)(l * 4 + u);
    outu[OU_AH + gbase] = pk2h(h0, h1);
    outu[OU_AL + gbase] = pk2h(q0, q1);
  }

  // ---- level 2 global min/max of distances
  {
    float cbr[4][DIM], c2[4];
    load_cbregs_pin(cb2, lane, 1.0f, cbr);
    cb_norms(cbr, c2);
    float dmn = 3.4e38f, dmx = -3.4e38f;
    for (int rb = 0; rb < 8; ++rb) {
      const int r0 = wid * 32 + rb * 4;
      float v[4][4];
#pragma unroll
      for (int q = 0; q < 4; ++q) { v[q][0] = 0.f; v[q][1] = 0.f; v[q][2] = 0.f; v[q][3] = 0.f; }
      dot4x4(&zl[r0 * LROW], cbr, v);
#pragma unroll
      for (int q = 0; q < 4; ++q) {
        float r2 = rsq[r0 + q];
#pragma unroll
        for (int c = 0; c < 4; ++c) {
          float dd = fmaf(-2.f, v[q][c], r2 + c2[c]);
          dmn = fminf(dmn, dd); dmx = fmaxf(dmx, dd);
        }
      }
    }
    dmn = wred_min(dmn);
    dmx = wred_max(dmx);
    if (lane == 0) {
      atomicMin(&wsu[WS_MINK], fkey(dmn));
      atomicMax(&wsu[WS_MAXK], fkey(dmx));
    }
  }

  loss_acc = wred_sum(loss_acc);
  if (lane == 0) red[wid] = loss_acc;
  __syncthreads();
  if (tid == 0) atomicAdd(&wsf[WS_SSQ], red[0] + red[1] + red[2] + red[3]);
}

__global__ void prep_k(const float* __restrict__ cb2, unsigned* __restrict__ wsu,
                       float* __restrict__ wsf, unsigned* __restrict__ bh,
                       unsigned* __restrict__ bl) {
  int j = threadIdx.x;  // 256 threads
  float dmin = fkeyinv(wsu[WS_MINK]);
  float dmax = fkeyinv(wsu[WS_MAXK]);
  float mid = (dmax + dmin) * 0.5f;
  float amp = fmaxf(dmax - mid, 1e-5f);
  float t = 1.0f / (amp * SKEPS);
  const float L2E = 1.4426950408889634f;
  float T2L = 2.0f * t * L2E;
  if (j == 0) wsf[WS_TWOT] = T2L;
  float s = 0.f;
#pragma unroll
  for (int d = 0; d < DIM; ++d) { float c = cb2[j * DIM + d]; s = fmaf(c, c, s); }
  wsf[WS_W0 + j] = -t * L2E * s;
  // B fragments: value = T2L * cb2[col][k]; same presumed k-map as A.
  for (int g = 0; g < 16; ++g) {
    int slot = g * 256 + j;           // 4096 u32 per plane
    int jt = slot >> 8, l = (slot >> 2) & 63, u = slot & 3;
    int col = jt * 16 + (l & 15);
    int k = (l >> 4) * 8 + u * 2;
    float b0 = T2L * cb2[col * DIM + k], b1 = T2L * cb2[col * DIM + k + 1];
    _Float16 h0 = (_Float16)b0, h1 = (_Float16)b1;
    _Float16 q0 = (_Float16)(b0 - (float)h0), q1 = (_Float16)(b1 - (float)h1);
    bh[slot] = pk2h(h0, h1);
    bl[slot] = pk2h(q0, q1);
  }
}

__global__ __launch_bounds__(256, 2) void iter_k(const uint4* __restrict__ afh,
                                                 const uint4* __restrict__ afl,
                                                 const uint4* __restrict__ bfh,
                                                 const uint4* __restrict__ bfl,
                                                 const float* __restrict__ w_rd,
                                                 float* __restrict__ w_wr,
                                                 const unsigned long long* __restrict__ s_rd,
                                                 unsigned long long* __restrict__ s_wr,
                                                 unsigned long long* __restrict__ s_zr,
                                                 int first) {
  __shared__ float wsh[KK];
  __shared__ float exm[8][2][2][16];   // [batch][pair][half][row16]
  __shared__ float exs[8][2][2][16];
  __shared__ float ssh[2][KK];
  const int tid = threadIdx.x, lane = tid & 63, wv = tid >> 6;
  const int pair = wv >> 1, ch = wv & 1, g = lane >> 4;

  {
    float wj = first ? w_rd[tid]
                     : w_rd[tid] + 34.0f - log2f(fmaxf((float)s_rd[tid], 1.0f));
    wsh[tid] = wj;
    if (blockIdx.x == 0) { w_wr[tid] = wj; s_zr[tid] = 0ull; }
  }
  // resident B fragments: this wave's 8 column-tiles (hi+lo = 64 VGPR)
  half8 Bh[8], Bl[8];
#pragma unroll
  for (int jt = 0; jt < 8; ++jt) {
    Bh[jt] = __builtin_bit_cast(half8, bfh[(ch * 8 + jt) * 64 + lane]);
    Bl[jt] = __builtin_bit_cast(half8, bfl[(ch * 8 + jt) * 64 + lane]);
  }
  __syncthreads();
  float wc[8];
#pragma unroll
  for (int jt = 0; jt < 8; ++jt) wc[jt] = wsh[(ch * 8 + jt) * 16 + (lane & 15)];

  float sg[8] = {0.f, 0.f, 0.f, 0.f, 0.f, 0.f, 0.f, 0.f};

  for (int b = 0; b < 8; ++b) {
    const int batchid = blockIdx.x * 16 + pair * 8 + b;
    half8 Ah = __builtin_bit_cast(half8, afh[batchid * 64 + lane]);
    half8 Al = __builtin_bit_cast(half8, afl[batchid * 64 + lane]);
    f32x4 v[8];
#pragma unroll
    for (int jt = 0; jt < 8; ++jt) {
      f32x4 acc = {0.f, 0.f, 0.f, 0.f};
      acc = __builtin_amdgcn_mfma_f32_16x16x32_f16(Al, Bl[jt], acc, 0, 0, 0);
      acc = __builtin_amdgcn_mfma_f32_16x16x32_f16(Al, Bh[jt], acc, 0, 0, 0);
      acc = __builtin_amdgcn_mfma_f32_16x16x32_f16(Ah, Bl[jt], acc, 0, 0, 0);
      acc = __builtin_amdgcn_mfma_f32_16x16x32_f16(Ah, Bh[jt], acc, 0, 0, 0);
      v[jt] = acc;
    }
    // scores = v + w; per-row (reg r) max over this wave's 128 cols
    float m[4];
#pragma unroll
    for (int r = 0; r < 4; ++r) {
#pragma unroll
      for (int jt = 0; jt < 8; ++jt) v[jt][r] += wc[jt];
      float a01 = fmaxf(v[0][r], v[1][r]), a23 = fmaxf(v[2][r], v[3][r]);
      float a45 = fmaxf(v[4][r], v[5][r]), a67 = fmaxf(v[6][r], v[7][r]);
      m[r] = g16_max(fmaxf(fmaxf(a01, a23), fmaxf(a45, a67)));
    }
    // exp vs own-half max; own-half sums
    float s[4];
#pragma unroll
    for (int r = 0; r < 4; ++r) {
#pragma unroll
      for (int jt = 0; jt < 8; ++jt) v[jt][r] = EXP2(v[jt][r] - m[r]);
      float s01 = v[0][r] + v[1][r], s23 = v[2][r] + v[3][r];
      float s45 = v[4][r] + v[5][r], s67 = v[6][r] + v[7][r];
      s[r] = g16_sum((s01 + s23) + (s45 + s67));
    }
    if ((lane & 15) == 0) {
      *reinterpret_cast<float4*>(&exm[b][pair][ch][g * 4]) = make_float4(m[0], m[1], m[2], m[3]);
      *reinterpret_cast<float4*>(&exs[b][pair][ch][g * 4]) = make_float4(s[0], s[1], s[2], s[3]);
    }
    __syncthreads();
    float4 pm = *reinterpret_cast<const float4*>(&exm[b][pair][ch ^ 1][g * 4]);
    float4 ps = *reinterpret_cast<const float4*>(&exs[b][pair][ch ^ 1][g * 4]);
    float rinv[4];
    {
      float pmv[4] = {pm.x, pm.y, pm.z, pm.w};
      float psv[4] = {ps.x, ps.y, ps.z, ps.w};
#pragma unroll
      for (int r = 0; r < 4; ++r) {
        float M = fmaxf(m[r], pmv[r]);
        float sc = EXP2(m[r] - M);
        float tot = fmaf(s[r], sc, psv[r] * EXP2(pmv[r] - M));
        rinv[r] = sc * __builtin_amdgcn_rcpf(tot);
      }
    }
#pragma unroll
    for (int jt = 0; jt < 8; ++jt)
#pragma unroll
      for (int r = 0; r < 4; ++r) sg[jt] = fmaf(v[jt][r], rinv[r], sg[jt]);
  }
  // cross-lane-group reduce of sigma, then block reduce
#pragma unroll
  for (int jt = 0; jt < 8; ++jt) {
    float x = sg[jt];
    x += __shfl_xor(x, 16); x += __shfl_xor(x, 32);
    sg[jt] = x;
  }
  if (lane < 16) {
#pragma unroll
    for (int jt = 0; jt < 8; ++jt) ssh[pair][ch * 128 + jt * 16 + lane] = sg[jt];
  }
  __syncthreads();
  float stot = ssh[0][tid] + ssh[1][tid];
  atomicAdd(&s_wr[tid], (unsigned long long)fmaf(stot, 16777216.0f, 0.5f));
}

__global__ __launch_bounds__(256, 2) void final_k(const float* __restrict__ z,
                                                  const float* __restrict__ cb0,
                                                  const float* __restrict__ cb1,
                                                  const float* __restrict__ cb2,
                                                  float* __restrict__ out,
                                                  const float* __restrict__ wsf,
                                                  float* __restrict__ wssq,
                                                  const float* __restrict__ w_rd,
                                                  const unsigned long long* __restrict__ s_rd) {
  __shared__ float zl[CHUNK * LROW];
  __shared__ float wsh[KK];
  __shared__ int codel[CHUNK];
  __shared__ float red[4];
  const int tid = threadIdx.x, lane = tid & 63, wid = tid >> 6;
  const long base = (long)blockIdx.x * CHUNK;

  wsh[tid] = w_rd[tid] + 34.0f - log2f(fmaxf((float)s_rd[tid], 1.0f));

  // stage z, then subtract gathered cb0[c0]+cb1[c1] -> r2 (bit-exact vs stageA)
#pragma unroll
  for (int g = 0; g < 4; ++g) {
    int f4 = g * 256 + tid;
    float4 vv = reinterpret_cast<const float4*>(z + base * DIM)[f4];
    int row = f4 >> 3, d = (f4 & 7) * 4;
    *reinterpret_cast<float4*>(&zl[row * LROW + d]) = vv;
  }
  __syncthreads();
  {
    int row = tid & (CHUNK - 1);
    int half = tid >> 7;
    int c0 = (int)out[OC0 + base + row];
    int c1 = (int)out[OC1 + base + row];
    const float4* e0 = reinterpret_cast<const float4*>(cb0 + c0 * DIM + half * 16);
    const float4* e1 = reinterpret_cast<const float4*>(cb1 + c1 * DIM + half * 16);
    float4* zr = reinterpret_cast<float4*>(&zl[row * LROW + half * 16]);
#pragma unroll
    for (int k = 0; k < 4; ++k) {
      float4 a = e0[k], bb = e1[k], v = zr[k];
      v.x = (v.x - a.x) - bb.x; v.y = (v.y - a.y) - bb.y;
      v.z = (v.z - a.z) - bb.z; v.w = (v.w - a.w) - bb.w;
      zr[k] = v;
    }
  }
  const float twot = wsf[WS_TWOT];
  float cbr[4][DIM];
  load_cbregs_pin(cb2, lane, twot, cbr);
  __syncthreads();
  float wc[4];
#pragma unroll
  for (int c = 0; c < 4; ++c) wc[c] = wsh[4 * lane + c];

  for (int rb = 0; rb < 8; ++rb) {
    const int r0 = wid * 32 + rb * 4;
    float v[4][4];
#pragma unroll
    for (int q = 0; q < 4; ++q) { v[q][0] = wc[0]; v[q][1] = wc[1]; v[q][2] = wc[2]; v[q][3] = wc[3]; }
    dot4x4(&zl[r0 * LROW], cbr, v);
    float bq[4], mq[4];
#pragma unroll
    for (int q = 0; q < 4; ++q)
      bq[q] = fmaxf(fmaxf(v[q][0], v[q][1]), fmaxf(v[q][2], v[q][3]));
#pragma unroll
    for (int q = 0; q < 4; ++q) mq[q] = wred_max(bq[q]);
#pragma unroll
    for (int q = 0; q < 4; ++q) {
      int cbi = (v[q][0] == mq[q]) ? 0 : ((v[q][1] == mq[q]) ? 1 : ((v[q][2] == mq[q]) ? 2 : 3));
      unsigned long long bl = __ballot(bq[q] == mq[q]);
      int src = __ffsll(bl) - 1;
      int code = __shfl(4 * lane + cbi, src);
      if (lane == 0) codel[r0 + q] = code;
    }
  }
  __syncthreads();
  if (tid < CHUNK) out[OC2 + base + tid] = (float)codel[tid];
  float loss_acc = 0.f;
#pragma unroll
  for (int g = 0; g < 4; ++g) {
    int f4 = g * 256 + tid;
    int row = f4 >> 3, d = (f4 & 7) * 4;
    float4 e = *reinterpret_cast<const float4*>(cb2 + codel[row] * DIM + d);
    float4 r = *reinterpret_cast<const float4*>(&zl[row * LROW + d]);
    float4 zv = reinterpret_cast<const float4*>(z + base * DIM)[f4];
    float4 q;
    q.x = zv.x - r.x + e.x; q.y = zv.y - r.y + e.y;
    q.z = zv.z - r.z + e.z; q.w = zv.w - r.w + e.w;
    reinterpret_cast<float4*>(out + OQ + base * DIM)[f4] = q;
    float rx = r.x - e.x, ry = r.y - e.y, rz = r.z - e.z, rw = r.w - e.w;
    loss_acc = fmaf(rx, rx, loss_acc); loss_acc = fmaf(ry, ry, loss_acc);
    loss_acc = fmaf(rz, rz, loss_acc); loss_acc = fmaf(rw, rw, loss_acc);
  }
  loss_acc = wred_sum(loss_acc);
  if (lane == 0) red[wid] = loss_acc;
  __syncthreads();
  if (tid == 0) atomicAdd(&wssq[WS_SSQ], red[0] + red[1] + red[2] + red[3]);
}

__global__ void losswrite_k(float* __restrict__ out, const float* __restrict__ wsf) {
  if (threadIdx.x == 0) out[OLOSS] = 1.25f * wsf[WS_SSQ] / 8388608.0f;
}

extern "C" void kernel_launch(void* const* d_in, const int* in_sizes, int n_in,
                              void* d_out, int out_size, void* d_ws, size_t ws_size,
                              hipStream_t stream) {
  const float* z   = (const float*)d_in[0];
  const float* cb0 = (const float*)d_in[1];
  const float* cb1 = (const float*)d_in[2];
  const float* cb2 = (const float*)d_in[3];
  float* out = (float*)d_out;
  unsigned* outu = (unsigned*)d_out;
  float* wsf = (float*)d_ws;
  unsigned* wsu = (unsigned*)d_ws;
  unsigned long long* sig = (unsigned long long*)((char*)d_ws + WS_SIGB);
  unsigned* bh = (unsigned*)d_ws + WS_BHU;
  unsigned* bl = (unsigned*)d_ws + WS_BLU;

  const uint4* afh = (const uint4*)(outu + OU_AH);
  const uint4* afl = (const uint4*)(outu + OU_AL);
  const uint4* bfh = (const uint4*)bh;
  const uint4* bfl = (const uint4*)bl;

  init_k<<<1, 256, 0, stream>>>(wsu, sig);
  stageA_k<<<NBLK, 256, 0, stream>>>(z, cb0, cb1, cb2, out, outu, wsu, wsf);
  prep_k<<<1, 256, 0, stream>>>(cb2, wsu, wsf, bh, bl);
  for (int it = 0; it < NIT; ++it) {
    const float* w_rd = (it == 0) ? (wsf + WS_W0) : (wsf + WS_WA + ((it - 1) & 1) * KK);
    float* w_wr = wsf + WS_WA + (it & 1) * KK;
    const unsigned long long* s_rd = sig + KK * ((it + 2) % 3);
    unsigned long long* s_wr = sig + KK * (it % 3);
    unsigned long long* s_zr = sig + KK * ((it + 1) % 3);
    iter_k<<<NIBLK, 256, 0, stream>>>(afh, afl, bfh, bfl, w_rd, w_wr, s_rd, s_wr, s_zr,
                                      it == 0 ? 1 : 0);
  }
  final_k<<<NBLK, 256, 0, stream>>>(z, cb0, cb1, cb2, out, wsf, wsf,
                                    wsf + WS_WA + ((NIT - 1) & 1) * KK,
                                    sig + KK * ((NIT - 1) % 3));
  losswrite_k<<<1, 64, 0, stream>>>(out, wsf);
}